// Round 13
// baseline (2063.218 us; speedup 1.0000x reference)
//
#include <hip/hip_runtime.h>
#include <math.h>

#define NPTS 4096
#define DIM  256
#define MAX_ITERS 10
#define EPSN 1e-8f
#define NSPL 16   // splits for NMS kernels

typedef __bf16 bf16x8 __attribute__((ext_vector_type(8)));
typedef float  f32x4  __attribute__((ext_vector_type(4)));
typedef unsigned short u16x8 __attribute__((ext_vector_type(8)));
typedef unsigned short u16x4 __attribute__((ext_vector_type(4)));
typedef unsigned short U16;

__device__ __forceinline__ U16 bf16_rne(float f) {
    unsigned int u = __float_as_uint(f);
    u += 0x7FFFu + ((u >> 16) & 1u);
    return (U16)(u >> 16);
}

__device__ __forceinline__ void glds16(const void* g, void* l) {
    __builtin_amdgcn_global_load_lds(
        (const __attribute__((address_space(1))) unsigned int*)g,
        (__attribute__((address_space(3))) unsigned int*)l,
        16, 0, 0);
}

// ---------------- prep ----------------
__global__ void initK(int* counts, int* keep, int* done, int* shiftb, int* acc) {
    int i = blockIdx.x * 256 + threadIdx.x;
    if (i < NPTS) { counts[i] = 0; keep[i] = 0; }
    if (i == 0) { *done = 0; *shiftb = 0; *acc = 0; }
}

// x -> c0 (copy), xhat hi/lo splits
__global__ void normxK(const float* __restrict__ x, float* __restrict__ c0,
                       U16* __restrict__ xh, U16* __restrict__ xl) {
    int m = blockIdx.x, t = threadIdx.x;
    float v = x[(size_t)m*DIM + t];
    __shared__ float red[256];
    red[t] = v*v; __syncthreads();
    for (int s = 128; s > 0; s >>= 1) { if (t < s) red[t] += red[t+s]; __syncthreads(); }
    float rn = 1.0f / fmaxf(sqrtf(red[0]), EPSN);
    float hv = v*rn;
    U16 hb = bf16_rne(hv);
    float hf = __uint_as_float((unsigned)hb << 16);
    U16 lb = bf16_rne(hv - hf);
    c0[(size_t)m*DIM + t] = v;
    xh[(size_t)m*DIM + t] = hb;
    xl[(size_t)m*DIM + t] = lb;
}

// x^T split: Xt[d][p] = x[p][d] as bf16 hi/lo
__global__ void transpK(const float* __restrict__ x, U16* __restrict__ Xth, U16* __restrict__ Xtl) {
    int bm = blockIdx.x, bd = blockIdx.y;
    int t = threadIdx.x;
    __shared__ float sh[32][33];
    int r = t >> 3, cq = (t & 7) * 4;
    float4 v = *(const float4*)&x[(size_t)(bm*32 + r)*DIM + bd*32 + cq];
    sh[r][cq] = v.x; sh[r][cq+1] = v.y; sh[r][cq+2] = v.z; sh[r][cq+3] = v.w;
    __syncthreads();
    int dd = t >> 3, mq = (t & 7) * 4;
    u16x4 h4, l4;
    #pragma unroll
    for (int j = 0; j < 4; ++j) {
        float f = sh[mq + j][dd];
        U16 hb = bf16_rne(f);
        h4[j] = hb;
        l4[j] = bf16_rne(f - __uint_as_float((unsigned)hb << 16));
    }
    size_t off = (size_t)(bd*32 + dd)*NPTS + bm*32 + mq;
    *(u16x4*)&Xth[off] = h4;
    *(u16x4*)&Xtl[off] = l4;
}

// ---------------- fusedK: one mean-shift iteration slice ----------------
// m-tile = 32 (R12): per-thread acc 48 regs (acc2[2][4]+acc1[2][2]); live set
// ~110-150 -> multiple waves/SIMD can co-schedule. LDS 34.3 KB STATIC
// (chat-hi 16K + W 17K + psw 0.5K) -> 3-4 blocks/CU by LDS. chat-lo from
// global (16 KB/block, L1-resident). launch_bounds(256,2) = 256-reg safety
// cap only; actual usage decides co-residency.
// Grid (SPL=8, NPTS/32=128) = 1024 blocks.
#define WPAD 136
__global__ __launch_bounds__(256, 2) void fusedK(
    const U16* __restrict__ chh, const U16* __restrict__ chl,
    const U16* __restrict__ xh,  const U16* __restrict__ xl,
    const U16* __restrict__ xth, const U16* __restrict__ xtl,
    float* __restrict__ cnum, float* __restrict__ psum,
    const int* __restrict__ done, const float* __restrict__ sigma,
    int KLEN)
{
    __shared__ U16 ChAh[32 * 256];        // [32 kb][32 row][8] bf16 hi (16 KB)
    __shared__ U16 WhL[32 * WPAD];        // (8.5 KB)
    __shared__ U16 WlL[32 * WPAD];        // (8.5 KB)
    __shared__ float psw[4][32];          // (0.5 KB)

    if (*done) return;
    const int tid  = threadIdx.x;
    const int lane = tid & 63, wq = tid >> 6;      // wq in 0..3
    const int l15  = lane & 15, lg = lane >> 4;
    const int slice = blockIdx.x;
    const int mblk  = blockIdx.y * 32;
    const int j0g  = slice * KLEN;

    const float ig = 1.0f / (2.0f * (*sigma) * (*sigma));

    // ---- stage chat-hi tile into LDS, slot layout [kb][row 0..31][8] ----
    {
        const int r = lane & 31, ko = lane >> 5;   // per-lane source terms
        #pragma unroll
        for (int q = 0; q < 4; ++q) {
            const int kb0 = wq*8 + q*2;            // wave-uniform dest base
            glds16(chh + (size_t)(mblk + r)*DIM + (kb0 + ko)*8,
                   ChAh + (size_t)kb0*256);
        }
    }
    __syncthreads();

    f32x4 acc2[2][4];
    #pragma unroll
    for (int a = 0; a < 2; ++a)
        #pragma unroll
        for (int b = 0; b < 4; ++b) { f32x4 z = {0.f,0.f,0.f,0.f}; acc2[a][b] = z; }
    float rs[2][4];
    #pragma unroll
    for (int a = 0; a < 2; ++a)
        #pragma unroll
        for (int i = 0; i < 4; ++i) rs[a][i] = 0.f;

    const int NJT = KLEN / 128;
    for (int jt = 0; jt < NJT; ++jt) {
        const int jb = j0g + jt * 128;

        // ---- phase A: S(32x128) = chat_tile . xhat_jtile^T ----
        // A-hi from LDS; A-lo from global (L1-resident 16 KB).
        f32x4 acc1[2][2];
        #pragma unroll
        for (int a = 0; a < 2; ++a)
            #pragma unroll
            for (int b = 0; b < 2; ++b) { f32x4 z = {0.f,0.f,0.f,0.f}; acc1[a][b] = z; }

        #pragma unroll
        for (int ks = 0; ks < 8; ++ks) {
            const int k0 = ks * 32 + lg * 8;
            const int kb = ks*4 + lg;
            bf16x8 ah[2], al[2], bh[2], bl[2];
            #pragma unroll
            for (int a = 0; a < 2; ++a) {
                ah[a] = *(const bf16x8*)&ChAh[(size_t)(kb*256 + (a*16 + l15)*8)];
                al[a] = *(const bf16x8*)(chl + (size_t)(mblk + a*16 + l15)*DIM + k0);
            }
            #pragma unroll
            for (int b = 0; b < 2; ++b) {
                size_t off = (size_t)(jb + wq*32 + b*16 + l15)*DIM + k0;
                bh[b] = *(const bf16x8*)(xh + off);
                bl[b] = *(const bf16x8*)(xl + off);
            }
            #pragma unroll
            for (int a = 0; a < 2; ++a)
                #pragma unroll
                for (int b = 0; b < 2; ++b) {
                    acc1[a][b] = __builtin_amdgcn_mfma_f32_16x16x32_bf16(ah[a], bh[b], acc1[a][b], 0,0,0);
                    acc1[a][b] = __builtin_amdgcn_mfma_f32_16x16x32_bf16(ah[a], bl[b], acc1[a][b], 0,0,0);
                    acc1[a][b] = __builtin_amdgcn_mfma_f32_16x16x32_bf16(al[a], bh[b], acc1[a][b], 0,0,0);
                }
        }

        // ---- epilogue: w = exp(2(s-1)ig), split, stash in LDS ----
        __syncthreads();   // previous tile's phase-B readers must be done
        #pragma unroll
        for (int a = 0; a < 2; ++a)
            #pragma unroll
            for (int b = 0; b < 2; ++b)
                #pragma unroll
                for (int i = 0; i < 4; ++i) {
                    float w = __expf(2.0f * (acc1[a][b][i] - 1.0f) * ig);
                    U16 hb = bf16_rne(w);
                    float hf = __uint_as_float((unsigned)hb << 16);
                    U16 lb = bf16_rne(w - hf);
                    int m = a*16 + lg*4 + i;
                    int j = wq*32 + b*16 + l15;
                    WhL[m*WPAD + j] = hb;
                    WlL[m*WPAD + j] = lb;
                    rs[a][i] += w;
                }
        __syncthreads();

        // ---- phase B: acc2 += W(32x128) . X_jtile(128x256) ----
        #pragma unroll
        for (int ks = 0; ks < 4; ++ks) {
            bf16x8 wh[2], wl[2], xbh[4], xbl[4];
            const int jl = ks*32 + lg*8;
            #pragma unroll
            for (int a = 0; a < 2; ++a) {
                int m = a*16 + l15;
                wh[a] = *(const bf16x8*)&WhL[m*WPAD + jl];
                wl[a] = *(const bf16x8*)&WlL[m*WPAD + jl];
            }
            #pragma unroll
            for (int b = 0; b < 4; ++b) {
                size_t off = (size_t)(wq*64 + b*16 + l15)*NPTS + jb + jl;
                xbh[b] = *(const bf16x8*)(xth + off);
                xbl[b] = *(const bf16x8*)(xtl + off);
            }
            #pragma unroll
            for (int a = 0; a < 2; ++a)
                #pragma unroll
                for (int b = 0; b < 4; ++b) {
                    acc2[a][b] = __builtin_amdgcn_mfma_f32_16x16x32_bf16(wh[a], xbh[b], acc2[a][b], 0,0,0);
                    acc2[a][b] = __builtin_amdgcn_mfma_f32_16x16x32_bf16(wh[a], xbl[b], acc2[a][b], 0,0,0);
                    acc2[a][b] = __builtin_amdgcn_mfma_f32_16x16x32_bf16(wl[a], xbh[b], acc2[a][b], 0,0,0);
                }
        }
    }

    // ---- row sums -> psum[slice][m] ----
    #pragma unroll
    for (int msk = 1; msk < 16; msk <<= 1)
        #pragma unroll
        for (int a = 0; a < 2; ++a)
            #pragma unroll
            for (int i = 0; i < 4; ++i)
                rs[a][i] += __shfl_xor(rs[a][i], msk, 64);
    __syncthreads();
    if (l15 == 0) {
        #pragma unroll
        for (int a = 0; a < 2; ++a)
            #pragma unroll
            for (int i = 0; i < 4; ++i)
                psw[wq][a*16 + lg*4 + i] = rs[a][i];
    }
    __syncthreads();
    if (tid < 32)
        psum[(size_t)slice*NPTS + mblk + tid] =
            psw[0][tid] + psw[1][tid] + psw[2][tid] + psw[3][tid];

    // ---- store cnum[slice] ----
    #pragma unroll
    for (int a = 0; a < 2; ++a)
        #pragma unroll
        for (int b = 0; b < 4; ++b)
            #pragma unroll
            for (int i = 0; i < 4; ++i) {
                int m = mblk + a*16 + lg*4 + i;
                int d = wq*64 + b*16 + l15;
                cnum[((size_t)slice*NPTS + m)*DIM + d] = acc2[a][b][i];
            }
}

// ---------------- reduce: cnew = cnum/rowsum, shift, normalize+split ----------------
__global__ void reduceK(const float* __restrict__ psum, const float* __restrict__ cnum,
                        const float* __restrict__ cprev, float* __restrict__ ccur,
                        U16* __restrict__ chh, U16* __restrict__ chl,
                        const int* __restrict__ done, int* __restrict__ shiftb, int spl)
{
    if (*done) return;
    int m = blockIdx.x, t = threadIdx.x;
    float rowsum = 0.f;
    for (int s = 0; s < spl; ++s) rowsum += psum[(size_t)s*NPTS + m];
    float num = 0.f;
    for (int s = 0; s < spl; ++s) num += cnum[((size_t)s*NPTS + m)*DIM + t];
    float cn = num / rowsum;
    ccur[(size_t)m*DIM + t] = cn;
    float d = cn - cprev[(size_t)m*DIM + t];
    __shared__ float redd[256], redn[256];
    redd[t] = d*d; redn[t] = cn*cn;
    __syncthreads();
    for (int st = 128; st > 0; st >>= 1) {
        if (t < st) { redd[t] += redd[t+st]; redn[t] += redn[t+st]; }
        __syncthreads();
    }
    if (t == 0) atomicMax(shiftb, __float_as_int(sqrtf(redd[0])));
    float rn = 1.0f / fmaxf(sqrtf(redn[0]), EPSN);
    float hv = cn * rn;
    U16 hb = bf16_rne(hv);
    float hf = __uint_as_float((unsigned)hb << 16);
    U16 lb = bf16_rne(hv - hf);
    chh[(size_t)m*DIM + t] = hb;
    chl[(size_t)m*DIM + t] = lb;
}

// accept/reject: on accept record buffer index, on reject freeze
__global__ void flagK(int* done, int* shiftb, int* acc, int curidx) {
    if (!*done) {
        float sh = __int_as_float(*shiftb);
        if (sh < 1e-5f) *done = 1;
        else *acc = curidx;
    }
    *shiftb = 0;
}

// out[0:N*D] = accepted centroid buffer
__global__ void finalK(const float* __restrict__ p0, const float* __restrict__ p1,
                       const float* __restrict__ p2, const int* __restrict__ acc,
                       float* __restrict__ out) {
    int i = blockIdx.x*256 + threadIdx.x;
    const float* p = (*acc == 0) ? p0 : ((*acc == 1) ? p1 : p2);
    out[i] = p[i];
}

// normalize accepted centroids -> hi/lo splits (for NMS)
__global__ void normfinalK(const float* __restrict__ p0, const float* __restrict__ p1,
                           const float* __restrict__ p2, const int* __restrict__ acc,
                           U16* __restrict__ hh, U16* __restrict__ ll) {
    int m = blockIdx.x, t = threadIdx.x;
    const float* p = (*acc == 0) ? p0 : ((*acc == 1) ? p1 : p2);
    float v = p[(size_t)m*DIM + t];
    __shared__ float red[256];
    red[t] = v*v; __syncthreads();
    for (int s = 128; s > 0; s >>= 1) { if (t < s) red[t] += red[t+s]; __syncthreads(); }
    float rn = 1.0f / fmaxf(sqrtf(red[0]), EPSN);
    float hv = v*rn;
    U16 hb = bf16_rne(hv);
    float hf = __uint_as_float((unsigned)hb << 16);
    U16 lb = bf16_rne(hv - hf);
    hh[(size_t)m*DIM + t] = hb;
    ll[(size_t)m*DIM + t] = lb;
}

// ---------------- NMS: MFMA per-point argmin over centroids ----------------
__global__ __launch_bounds__(256) void argminMK(
    const U16* __restrict__ Ph, const U16* __restrict__ Pl,
    const U16* __restrict__ Ch, const U16* __restrict__ Cl,
    float* __restrict__ aval, int* __restrict__ aidx)
{
    const int tid = threadIdx.x;
    const int lane = tid & 63, wid = tid >> 6;
    const int wr = wid & 1, wc = wid >> 1;
    const int P  = blockIdx.x * 128;
    const int ms = blockIdx.y;
    const int M0 = ms * (NPTS / NSPL);

    __shared__ U16 S[4][4096];
    __shared__ float fmv[128][2];
    __shared__ int   fmi[128][2];

    float pv[16];
    int   pm[16];
    #pragma unroll
    for (int s = 0; s < 16; ++s) { pv[s] = 3.4e38f; pm[s] = 0; }

    for (int mt = 0; mt < (NPTS/NSPL)/128; ++mt) {
        const int M = M0 + mt*128;
        f32x4 acc[4][4];
        #pragma unroll
        for (int a = 0; a < 4; ++a)
            #pragma unroll
            for (int b = 0; b < 4; ++b) { f32x4 z = {0.f,0.f,0.f,0.f}; acc[a][b] = z; }

        for (int k0 = 0; k0 < DIM; k0 += 32) {
            __syncthreads();
            #pragma unroll
            for (int h = 0; h < 2; ++h) {
                const int sb   = wid * 128 + h * 64;
                const int slot = sb + lane;
                const int row  = slot & 127, kg = slot >> 7;
                const int col  = k0 + kg * 8;
                glds16(Ph + (size_t)(P + row)*DIM + col, &S[0][(size_t)sb * 8]);
                glds16(Pl + (size_t)(P + row)*DIM + col, &S[1][(size_t)sb * 8]);
                glds16(Ch + (size_t)(M + row)*DIM + col, &S[2][(size_t)sb * 8]);
                glds16(Cl + (size_t)(M + row)*DIM + col, &S[3][(size_t)sb * 8]);
            }
            __syncthreads();
            bf16x8 fah[4], fal[4], fbh[4], fbl[4];
            const int roff = (lane >> 4) * 128 + (lane & 15);
            #pragma unroll
            for (int f = 0; f < 4; ++f) {
                const int sA = roff + wr*64 + f*16;
                const int sB = roff + wc*64 + f*16;
                fah[f] = *(const bf16x8*)&S[0][(size_t)sA * 8];
                fal[f] = *(const bf16x8*)&S[1][(size_t)sA * 8];
                fbh[f] = *(const bf16x8*)&S[2][(size_t)sB * 8];
                fbl[f] = *(const bf16x8*)&S[3][(size_t)sB * 8];
            }
            #pragma unroll
            for (int a = 0; a < 4; ++a)
                #pragma unroll
                for (int b = 0; b < 4; ++b) {
                    acc[a][b] = __builtin_amdgcn_mfma_f32_16x16x32_bf16(fah[a], fbh[b], acc[a][b], 0,0,0);
                    acc[a][b] = __builtin_amdgcn_mfma_f32_16x16x32_bf16(fah[a], fbl[b], acc[a][b], 0,0,0);
                    acc[a][b] = __builtin_amdgcn_mfma_f32_16x16x32_bf16(fal[a], fbh[b], acc[a][b], 0,0,0);
                }
        }
        #pragma unroll
        for (int a = 0; a < 4; ++a)
            #pragma unroll
            for (int i = 0; i < 4; ++i) {
                const int s = a*4 + i;
                #pragma unroll
                for (int b = 0; b < 4; ++b) {
                    float d = 2.0f*(1.0f - acc[a][b][i]);
                    int m = M + wc*64 + b*16 + (lane & 15);
                    if (d < pv[s] || (d == pv[s] && m < pm[s])) { pv[s]=d; pm[s]=m; }
                }
            }
    }
    #pragma unroll
    for (int msk = 1; msk < 16; msk <<= 1)
        #pragma unroll
        for (int s = 0; s < 16; ++s) {
            float v2 = __shfl_xor(pv[s], msk, 64);
            int   m2 = __shfl_xor(pm[s], msk, 64);
            if (v2 < pv[s] || (v2 == pv[s] && m2 < pm[s])) { pv[s]=v2; pm[s]=m2; }
        }
    if ((lane & 15) == 0) {
        #pragma unroll
        for (int a = 0; a < 4; ++a)
            #pragma unroll
            for (int i = 0; i < 4; ++i) {
                int row = wr*64 + a*16 + (lane>>4)*4 + i;
                fmv[row][wc] = pv[a*4+i];
                fmi[row][wc] = pm[a*4+i];
            }
    }
    __syncthreads();
    if (tid < 128) {
        float v = fmv[tid][0]; int m = fmi[tid][0];
        float v1 = fmv[tid][1]; int m1 = fmi[tid][1];
        if (v1 < v || (v1 == v && m1 < m)) { v=v1; m=m1; }
        aval[(size_t)ms*NPTS + P + tid] = v;
        aidx[(size_t)ms*NPTS + P + tid] = m;
    }
}

__global__ void acombineK(const float* __restrict__ aval, const int* __restrict__ aidx,
                          int* __restrict__ counts)
{
    int p = blockIdx.x*256 + threadIdx.x;
    float bv = 3.4e38f; int bm = 1<<30;
    for (int s = 0; s < NSPL; ++s) {
        float v = aval[(size_t)s*NPTS + p]; int m = aidx[(size_t)s*NPTS + p];
        if (v < bv || (v == bv && m < bm)) { bv=v; bm=m; }
    }
    atomicAdd(&counts[bm], 1);
}

// ---------------- NMS: MFMA per-centroid argmax of close*counts ----------------
__global__ __launch_bounds__(256) void ccMK(
    const U16* __restrict__ Ch, const U16* __restrict__ Cl,
    const int* __restrict__ counts, const float* __restrict__ sigma,
    float* __restrict__ cval, int* __restrict__ cidx)
{
    const int tid = threadIdx.x;
    const int lane = tid & 63, wid = tid >> 6;
    const int wr = wid & 1, wc = wid >> 1;
    const int Mrow = blockIdx.x * 128;
    const int js   = blockIdx.y;
    const int J0   = js * (NPTS / NSPL);
    const float bw = *sigma;

    __shared__ U16 S[4][4096];
    __shared__ float gmv[128][2];
    __shared__ int   gmi[128][2];
    __shared__ float scnt[128];

    float mvv[16];
    int   mjj[16];
    #pragma unroll
    for (int s = 0; s < 16; ++s) { mvv[s] = -1.f; mjj[s] = 1<<30; }

    for (int jt = 0; jt < (NPTS/NSPL)/128; ++jt) {
        const int J = J0 + jt*128;
        __syncthreads();
        if (tid < 128) scnt[tid] = (float)counts[J + tid];
        f32x4 acc[4][4];
        #pragma unroll
        for (int a = 0; a < 4; ++a)
            #pragma unroll
            for (int b = 0; b < 4; ++b) { f32x4 z = {0.f,0.f,0.f,0.f}; acc[a][b] = z; }

        for (int k0 = 0; k0 < DIM; k0 += 32) {
            __syncthreads();
            #pragma unroll
            for (int h = 0; h < 2; ++h) {
                const int sb   = wid * 128 + h * 64;
                const int slot = sb + lane;
                const int row  = slot & 127, kg = slot >> 7;
                const int col  = k0 + kg * 8;
                glds16(Ch + (size_t)(Mrow + row)*DIM + col, &S[0][(size_t)sb * 8]);
                glds16(Cl + (size_t)(Mrow + row)*DIM + col, &S[1][(size_t)sb * 8]);
                glds16(Ch + (size_t)(J + row)*DIM + col,    &S[2][(size_t)sb * 8]);
                glds16(Cl + (size_t)(J + row)*DIM + col,    &S[3][(size_t)sb * 8]);
            }
            __syncthreads();
            bf16x8 fah[4], fal[4], fbh[4], fbl[4];
            const int roff = (lane >> 4) * 128 + (lane & 15);
            #pragma unroll
            for (int f = 0; f < 4; ++f) {
                const int sA = roff + wr*64 + f*16;
                const int sB = roff + wc*64 + f*16;
                fah[f] = *(const bf16x8*)&S[0][(size_t)sA * 8];
                fal[f] = *(const bf16x8*)&S[1][(size_t)sA * 8];
                fbh[f] = *(const bf16x8*)&S[2][(size_t)sB * 8];
                fbl[f] = *(const bf16x8*)&S[3][(size_t)sB * 8];
            }
            #pragma unroll
            for (int a = 0; a < 4; ++a)
                #pragma unroll
                for (int b = 0; b < 4; ++b) {
                    acc[a][b] = __builtin_amdgcn_mfma_f32_16x16x32_bf16(fah[a], fbh[b], acc[a][b], 0,0,0);
                    acc[a][b] = __builtin_amdgcn_mfma_f32_16x16x32_bf16(fah[a], fbl[b], acc[a][b], 0,0,0);
                    acc[a][b] = __builtin_amdgcn_mfma_f32_16x16x32_bf16(fal[a], fbh[b], acc[a][b], 0,0,0);
                }
        }
        #pragma unroll
        for (int a = 0; a < 4; ++a)
            #pragma unroll
            for (int i = 0; i < 4; ++i) {
                const int s = a*4 + i;
                #pragma unroll
                for (int b = 0; b < 4; ++b) {
                    float d = 2.0f*(1.0f - acc[a][b][i]);
                    int jl = wc*64 + b*16 + (lane & 15);
                    float val = (d < bw) ? scnt[jl] : 0.0f;
                    int j = J + jl;
                    if (val > mvv[s] || (val == mvv[s] && j < mjj[s])) { mvv[s]=val; mjj[s]=j; }
                }
            }
    }
    #pragma unroll
    for (int msk = 1; msk < 16; msk <<= 1)
        #pragma unroll
        for (int s = 0; s < 16; ++s) {
            float v2 = __shfl_xor(mvv[s], msk, 64);
            int   j2 = __shfl_xor(mjj[s], msk, 64);
            if (v2 > mvv[s] || (v2 == mvv[s] && j2 < mjj[s])) { mvv[s]=v2; mjj[s]=j2; }
        }
    if ((lane & 15) == 0) {
        #pragma unroll
        for (int a = 0; a < 4; ++a)
            #pragma unroll
            for (int i = 0; i < 4; ++i) {
                int row = wr*64 + a*16 + (lane>>4)*4 + i;
                gmv[row][wc] = mvv[a*4+i];
                gmi[row][wc] = mjj[a*4+i];
            }
    }
    __syncthreads();
    if (tid < 128) {
        float v = gmv[tid][0]; int j = gmi[tid][0];
        float v1 = gmv[tid][1]; int j1 = gmi[tid][1];
        if (v1 > v || (v1 == v && j1 < j)) { v=v1; j=j1; }
        cval[(size_t)js*NPTS + Mrow + tid] = v;
        cidx[(size_t)js*NPTS + Mrow + tid] = j;
    }
}

__global__ void ccombineK(const float* __restrict__ cval, const int* __restrict__ cidx,
                          const int* __restrict__ counts, int* __restrict__ keep)
{
    int m = blockIdx.x*256 + threadIdx.x;
    float bv = -1.0f; int bj = 1<<30;
    for (int s = 0; s < NSPL; ++s) {
        float v = cval[(size_t)s*NPTS + m]; int j = cidx[(size_t)s*NPTS + m];
        if (v > bv || (v == bv && j < bj)) { bv=v; bj=j; }
    }
    if (counts[m] > 0) atomicOr(&keep[bj], 1);
}

__global__ void keepwriteK(const int* __restrict__ keep, float* __restrict__ out)
{
    int i = blockIdx.x*256 + threadIdx.x;
    out[(size_t)NPTS*DIM + i] = keep[i] ? 1.0f : 0.0f;
}

// ---------------- host ----------------
extern "C" void kernel_launch(void* const* d_in, const int* in_sizes, int n_in,
                              void* d_out, int out_size, void* d_ws, size_t ws_size,
                              hipStream_t stream)
{
    const float* x     = (const float*)d_in[0];
    const float* sigma = (const float*)d_in[1];
    float* out = (float*)d_out;

    const size_t ND4 = (size_t)NPTS * DIM * 4;   // 4 MB
    const size_t NDu = (size_t)NPTS * DIM * 2;   // 2 MB

    const int spls[] = {8, 4, 2};
    int SPL = 2;
    size_t o_xh=0,o_xl=0,o_xth=0,o_xtl=0,o_chh=0,o_chl=0,o_c0=0,o_c1=0,o_c2=0,
           o_cnum=0,o_psum=0,o_aval=0,o_aidx=0,o_cval=0,o_cidx=0,
           o_counts=0,o_keep=0,o_done=0,o_shift=0,o_acc=0;

    for (int ci = 0; ci < 3; ++ci) {
        int spl = spls[ci];
        size_t off = 0;
        auto take = [&](size_t nb) { size_t a = off; off += (nb + 255) & ~(size_t)255; return a; };
        o_xh  = take(NDu);  o_xl  = take(NDu);
        o_xth = take(NDu);  o_xtl = take(NDu);
        o_chh = take(NDu);  o_chl = take(NDu);
        o_c0  = take(ND4);  o_c1  = take(ND4);  o_c2 = take(ND4);
        o_cnum = take((size_t)spl * ND4);
        o_psum = take((size_t)spl * NPTS * 4);
        o_aval = take((size_t)NSPL*NPTS*4); o_aidx = take((size_t)NSPL*NPTS*4);
        o_cval = take((size_t)NSPL*NPTS*4); o_cidx = take((size_t)NSPL*NPTS*4);
        o_counts = take((size_t)NPTS*4);    o_keep = take((size_t)NPTS*4);
        o_done = take(256); o_shift = take(256); o_acc = take(256);
        SPL = spl;
        if (off <= ws_size) break;
    }
    const int KLEN = NPTS / SPL;

    char* W = (char*)d_ws;
    U16* xh  = (U16*)(W + o_xh);   U16* xl  = (U16*)(W + o_xl);
    U16* xth = (U16*)(W + o_xth);  U16* xtl = (U16*)(W + o_xtl);
    U16* chh = (U16*)(W + o_chh);  U16* chl = (U16*)(W + o_chl);
    float* cb[3] = { (float*)(W + o_c0), (float*)(W + o_c1), (float*)(W + o_c2) };
    float* cnum = (float*)(W + o_cnum);
    float* psum = (float*)(W + o_psum);
    float* aval = (float*)(W + o_aval); int* aidx = (int*)(W + o_aidx);
    float* cval = (float*)(W + o_cval); int* cidx = (int*)(W + o_cidx);
    int* counts = (int*)(W + o_counts); int* keep = (int*)(W + o_keep);
    int* done   = (int*)(W + o_done);   int* shiftb = (int*)(W + o_shift);
    int* acc    = (int*)(W + o_acc);

    initK  <<<dim3(16), dim3(256), 0, stream>>>(counts, keep, done, shiftb, acc);
    normxK <<<dim3(NPTS), dim3(256), 0, stream>>>(x, cb[0], xh, xl);
    transpK<<<dim3(128, 8), dim3(256), 0, stream>>>(x, xth, xtl);

    for (int it = 0; it < MAX_ITERS; ++it) {
        const U16* ah = (it == 0) ? xh : chh;
        const U16* al = (it == 0) ? xl : chl;
        const int cur = 1 + (it & 1);
        const int prv = (it == 0) ? 0 : 1 + ((it - 1) & 1);
        fusedK<<<dim3(SPL, NPTS/32), dim3(256), 0, stream>>>(
            ah, al, xh, xl, xth, xtl, cnum, psum, done, sigma, KLEN);
        reduceK<<<dim3(NPTS), dim3(256), 0, stream>>>(
            psum, cnum, cb[prv], cb[cur], chh, chl, done, shiftb, SPL);
        flagK<<<dim3(1), dim3(1), 0, stream>>>(done, shiftb, acc, cur);
    }

    finalK    <<<dim3(NPTS), dim3(256), 0, stream>>>(cb[0], cb[1], cb[2], acc, out);
    normfinalK<<<dim3(NPTS), dim3(256), 0, stream>>>(cb[0], cb[1], cb[2], acc, chh, chl);

    argminMK<<<dim3(NPTS/128, NSPL), dim3(256), 0, stream>>>(xh, xl, chh, chl, aval, aidx);
    acombineK<<<dim3(NPTS/256), dim3(256), 0, stream>>>(aval, aidx, counts);
    ccMK    <<<dim3(NPTS/128, NSPL), dim3(256), 0, stream>>>(chh, chl, counts, sigma, cval, cidx);
    ccombineK<<<dim3(NPTS/256), dim3(256), 0, stream>>>(cval, cidx, counts, keep);
    keepwriteK<<<dim3(NPTS/256), dim3(256), 0, stream>>>(keep, out);
}

// Round 14
// 1840.906 us; speedup vs baseline: 1.1208x; 1.1208x over previous
//
#include <hip/hip_runtime.h>
#include <math.h>

#define NPTS 4096
#define DIM  256
#define MAX_ITERS 10
#define EPSN 1e-8f
#define NSPL 16   // splits for NMS kernels

typedef __bf16 bf16x8 __attribute__((ext_vector_type(8)));
typedef float  f32x4  __attribute__((ext_vector_type(4)));
typedef unsigned short u16x8 __attribute__((ext_vector_type(8)));
typedef unsigned short u16x4 __attribute__((ext_vector_type(4)));
typedef unsigned short U16;

__device__ __forceinline__ U16 bf16_rne(float f) {
    unsigned int u = __float_as_uint(f);
    u += 0x7FFFu + ((u >> 16) & 1u);
    return (U16)(u >> 16);
}

__device__ __forceinline__ void glds16(const void* g, void* l) {
    __builtin_amdgcn_global_load_lds(
        (const __attribute__((address_space(1))) unsigned int*)g,
        (__attribute__((address_space(3))) unsigned int*)l,
        16, 0, 0);
}

// ---------------- prep ----------------
__global__ void initK(int* counts, int* keep, int* done, int* shiftb, int* acc) {
    int i = blockIdx.x * 256 + threadIdx.x;
    if (i < NPTS) { counts[i] = 0; keep[i] = 0; }
    if (i == 0) { *done = 0; *shiftb = 0; *acc = 0; }
}

// x -> c0 (copy), xhat hi/lo splits
__global__ void normxK(const float* __restrict__ x, float* __restrict__ c0,
                       U16* __restrict__ xh, U16* __restrict__ xl) {
    int m = blockIdx.x, t = threadIdx.x;
    float v = x[(size_t)m*DIM + t];
    __shared__ float red[256];
    red[t] = v*v; __syncthreads();
    for (int s = 128; s > 0; s >>= 1) { if (t < s) red[t] += red[t+s]; __syncthreads(); }
    float rn = 1.0f / fmaxf(sqrtf(red[0]), EPSN);
    float hv = v*rn;
    U16 hb = bf16_rne(hv);
    float hf = __uint_as_float((unsigned)hb << 16);
    U16 lb = bf16_rne(hv - hf);
    c0[(size_t)m*DIM + t] = v;
    xh[(size_t)m*DIM + t] = hb;
    xl[(size_t)m*DIM + t] = lb;
}

// x^T split: Xt[d][p] = x[p][d] as bf16 hi/lo
__global__ void transpK(const float* __restrict__ x, U16* __restrict__ Xth, U16* __restrict__ Xtl) {
    int bm = blockIdx.x, bd = blockIdx.y;
    int t = threadIdx.x;
    __shared__ float sh[32][33];
    int r = t >> 3, cq = (t & 7) * 4;
    float4 v = *(const float4*)&x[(size_t)(bm*32 + r)*DIM + bd*32 + cq];
    sh[r][cq] = v.x; sh[r][cq+1] = v.y; sh[r][cq+2] = v.z; sh[r][cq+3] = v.w;
    __syncthreads();
    int dd = t >> 3, mq = (t & 7) * 4;
    u16x4 h4, l4;
    #pragma unroll
    for (int j = 0; j < 4; ++j) {
        float f = sh[mq + j][dd];
        U16 hb = bf16_rne(f);
        h4[j] = hb;
        l4[j] = bf16_rne(f - __uint_as_float((unsigned)hb << 16));
    }
    size_t off = (size_t)(bd*32 + dd)*NPTS + bm*32 + mq;
    *(u16x4*)&Xth[off] = h4;
    *(u16x4*)&Xtl[off] = l4;
}

// ---------------- fusedK: one mean-shift iteration slice ----------------
// R13: m64 tile (R10 density) + j64 phase-tile (small acc: acc1[4]=16,
// acc2[4][4]=64 -> acc 80 + arch ~140 = ~220 <= 256) -> 2 waves/SIMD with
// __launch_bounds__(256,2) (cap 256 incl. unified AGPR; R12 proved this
// co-schedules). LDS 51 KB STATIC (chat-hi 32K + W 2x9K + psw 1K) -> 2
// blocks/CU. SPL=8 -> 512 blocks = exactly 2 blocks/CU.
// Register model (R12 lesson): trace VGPR_Count is arch-only; add acc regs.
#define WPADJ 72
__global__ __launch_bounds__(256, 2) void fusedK(
    const U16* __restrict__ chh, const U16* __restrict__ chl,
    const U16* __restrict__ xh,  const U16* __restrict__ xl,
    const U16* __restrict__ xth, const U16* __restrict__ xtl,
    float* __restrict__ cnum, float* __restrict__ psum,
    const int* __restrict__ done, const float* __restrict__ sigma,
    int KLEN)
{
    __shared__ U16 ChAh[32 * 512];        // [32 kb][64 row][8] bf16 hi (32 KB)
    __shared__ U16 WhL[64 * WPADJ];       // [64 m][72] (9 KB)
    __shared__ U16 WlL[64 * WPADJ];       // (9 KB)
    __shared__ float psw[4][64];          // (1 KB)

    if (*done) return;
    const int tid  = threadIdx.x;
    const int lane = tid & 63, wq = tid >> 6;      // wq in 0..3
    const int l15  = lane & 15, lg = lane >> 4;
    const int slice = blockIdx.x;
    const int mblk  = blockIdx.y * 64;
    const int j0g  = slice * KLEN;

    const float ig = 1.0f / (2.0f * (*sigma) * (*sigma));

    // ---- stage chat-hi tile into LDS, slot layout [kb][row 0..63][8] ----
    {
        const int r = mblk + lane;
        #pragma unroll
        for (int q = 0; q < 8; ++q) {
            const int kb = wq*8 + q;   // wave-uniform dest; HW scatters +lane*16
            glds16(chh + (size_t)r*DIM + kb*8, ChAh + (size_t)kb*512);
        }
    }
    __syncthreads();

    f32x4 acc2[4][4];
    #pragma unroll
    for (int a = 0; a < 4; ++a)
        #pragma unroll
        for (int b = 0; b < 4; ++b) { f32x4 z = {0.f,0.f,0.f,0.f}; acc2[a][b] = z; }
    float rs[4][4];
    #pragma unroll
    for (int a = 0; a < 4; ++a)
        #pragma unroll
        for (int i = 0; i < 4; ++i) rs[a][i] = 0.f;

    const int NJT = KLEN / 64;
    for (int jt = 0; jt < NJT; ++jt) {
        const int jb = j0g + jt * 64;

        // ---- phase A: S(64x64) = chat_tile . xhat_jtile^T ----
        // A-hi from LDS; A-lo from global (L1-resident 32 KB); wave owns 16 j.
        f32x4 acc1[4];
        #pragma unroll
        for (int a = 0; a < 4; ++a) { f32x4 z = {0.f,0.f,0.f,0.f}; acc1[a] = z; }

        #pragma unroll
        for (int ks = 0; ks < 8; ++ks) {
            const int k0 = ks * 32 + lg * 8;
            const int kb = ks*4 + lg;
            bf16x8 ah[4], al[4], bh, bl;
            #pragma unroll
            for (int a = 0; a < 4; ++a) {
                const int slot = kb*64 + a*16 + l15;
                ah[a] = *(const bf16x8*)&ChAh[(size_t)slot * 8];
                al[a] = *(const bf16x8*)(chl + (size_t)(mblk + a*16 + l15)*DIM + k0);
            }
            {
                size_t off = (size_t)(jb + wq*16 + l15)*DIM + k0;
                bh = *(const bf16x8*)(xh + off);
                bl = *(const bf16x8*)(xl + off);
            }
            #pragma unroll
            for (int a = 0; a < 4; ++a) {
                acc1[a] = __builtin_amdgcn_mfma_f32_16x16x32_bf16(ah[a], bh, acc1[a], 0,0,0);
                acc1[a] = __builtin_amdgcn_mfma_f32_16x16x32_bf16(ah[a], bl, acc1[a], 0,0,0);
                acc1[a] = __builtin_amdgcn_mfma_f32_16x16x32_bf16(al[a], bh, acc1[a], 0,0,0);
            }
        }

        // ---- epilogue: w = exp(2(s-1)ig), split, stash in LDS ----
        __syncthreads();   // previous tile's phase-B readers must be done
        #pragma unroll
        for (int a = 0; a < 4; ++a)
            #pragma unroll
            for (int i = 0; i < 4; ++i) {
                float w = __expf(2.0f * (acc1[a][i] - 1.0f) * ig);
                U16 hb = bf16_rne(w);
                float hf = __uint_as_float((unsigned)hb << 16);
                U16 lb = bf16_rne(w - hf);
                int m = a*16 + lg*4 + i;
                int j = wq*16 + l15;
                WhL[m*WPADJ + j] = hb;
                WlL[m*WPADJ + j] = lb;
                rs[a][i] += w;
            }
        __syncthreads();

        // ---- phase B: acc2 += W(64x64) . X_jtile(64x256) ----
        #pragma unroll
        for (int ks = 0; ks < 2; ++ks) {
            bf16x8 wh[4], wl[4], xbh[4], xbl[4];
            const int jl = ks*32 + lg*8;
            #pragma unroll
            for (int a = 0; a < 4; ++a) {
                int m = a*16 + l15;
                wh[a] = *(const bf16x8*)&WhL[m*WPADJ + jl];
                wl[a] = *(const bf16x8*)&WlL[m*WPADJ + jl];
            }
            #pragma unroll
            for (int b = 0; b < 4; ++b) {
                size_t off = (size_t)(wq*64 + b*16 + l15)*NPTS + jb + jl;
                xbh[b] = *(const bf16x8*)(xth + off);
                xbl[b] = *(const bf16x8*)(xtl + off);
            }
            #pragma unroll
            for (int a = 0; a < 4; ++a)
                #pragma unroll
                for (int b = 0; b < 4; ++b) {
                    acc2[a][b] = __builtin_amdgcn_mfma_f32_16x16x32_bf16(wh[a], xbh[b], acc2[a][b], 0,0,0);
                    acc2[a][b] = __builtin_amdgcn_mfma_f32_16x16x32_bf16(wh[a], xbl[b], acc2[a][b], 0,0,0);
                    acc2[a][b] = __builtin_amdgcn_mfma_f32_16x16x32_bf16(wl[a], xbh[b], acc2[a][b], 0,0,0);
                }
        }
    }

    // ---- row sums -> psum[slice][m] ----
    #pragma unroll
    for (int msk = 1; msk < 16; msk <<= 1)
        #pragma unroll
        for (int a = 0; a < 4; ++a)
            #pragma unroll
            for (int i = 0; i < 4; ++i)
                rs[a][i] += __shfl_xor(rs[a][i], msk, 64);
    __syncthreads();
    if (l15 == 0) {
        #pragma unroll
        for (int a = 0; a < 4; ++a)
            #pragma unroll
            for (int i = 0; i < 4; ++i)
                psw[wq][a*16 + lg*4 + i] = rs[a][i];
    }
    __syncthreads();
    if (tid < 64)
        psum[(size_t)slice*NPTS + mblk + tid] =
            psw[0][tid] + psw[1][tid] + psw[2][tid] + psw[3][tid];

    // ---- store cnum[slice] ----
    #pragma unroll
    for (int a = 0; a < 4; ++a)
        #pragma unroll
        for (int b = 0; b < 4; ++b)
            #pragma unroll
            for (int i = 0; i < 4; ++i) {
                int m = mblk + a*16 + lg*4 + i;
                int d = wq*64 + b*16 + l15;
                cnum[((size_t)slice*NPTS + m)*DIM + d] = acc2[a][b][i];
            }
}

// ---------------- reduce: cnew = cnum/rowsum, shift, normalize+split ----------------
__global__ void reduceK(const float* __restrict__ psum, const float* __restrict__ cnum,
                        const float* __restrict__ cprev, float* __restrict__ ccur,
                        U16* __restrict__ chh, U16* __restrict__ chl,
                        const int* __restrict__ done, int* __restrict__ shiftb, int spl)
{
    if (*done) return;
    int m = blockIdx.x, t = threadIdx.x;
    float rowsum = 0.f;
    for (int s = 0; s < spl; ++s) rowsum += psum[(size_t)s*NPTS + m];
    float num = 0.f;
    for (int s = 0; s < spl; ++s) num += cnum[((size_t)s*NPTS + m)*DIM + t];
    float cn = num / rowsum;
    ccur[(size_t)m*DIM + t] = cn;
    float d = cn - cprev[(size_t)m*DIM + t];
    __shared__ float redd[256], redn[256];
    redd[t] = d*d; redn[t] = cn*cn;
    __syncthreads();
    for (int st = 128; st > 0; st >>= 1) {
        if (t < st) { redd[t] += redd[t+st]; redn[t] += redn[t+st]; }
        __syncthreads();
    }
    if (t == 0) atomicMax(shiftb, __float_as_int(sqrtf(redd[0])));
    float rn = 1.0f / fmaxf(sqrtf(redn[0]), EPSN);
    float hv = cn * rn;
    U16 hb = bf16_rne(hv);
    float hf = __uint_as_float((unsigned)hb << 16);
    U16 lb = bf16_rne(hv - hf);
    chh[(size_t)m*DIM + t] = hb;
    chl[(size_t)m*DIM + t] = lb;
}

// accept/reject: on accept record buffer index, on reject freeze
__global__ void flagK(int* done, int* shiftb, int* acc, int curidx) {
    if (!*done) {
        float sh = __int_as_float(*shiftb);
        if (sh < 1e-5f) *done = 1;
        else *acc = curidx;
    }
    *shiftb = 0;
}

// out[0:N*D] = accepted centroid buffer
__global__ void finalK(const float* __restrict__ p0, const float* __restrict__ p1,
                       const float* __restrict__ p2, const int* __restrict__ acc,
                       float* __restrict__ out) {
    int i = blockIdx.x*256 + threadIdx.x;
    const float* p = (*acc == 0) ? p0 : ((*acc == 1) ? p1 : p2);
    out[i] = p[i];
}

// normalize accepted centroids -> hi/lo splits (for NMS)
__global__ void normfinalK(const float* __restrict__ p0, const float* __restrict__ p1,
                           const float* __restrict__ p2, const int* __restrict__ acc,
                           U16* __restrict__ hh, U16* __restrict__ ll) {
    int m = blockIdx.x, t = threadIdx.x;
    const float* p = (*acc == 0) ? p0 : ((*acc == 1) ? p1 : p2);
    float v = p[(size_t)m*DIM + t];
    __shared__ float red[256];
    red[t] = v*v; __syncthreads();
    for (int s = 128; s > 0; s >>= 1) { if (t < s) red[t] += red[t+s]; __syncthreads(); }
    float rn = 1.0f / fmaxf(sqrtf(red[0]), EPSN);
    float hv = v*rn;
    U16 hb = bf16_rne(hv);
    float hf = __uint_as_float((unsigned)hb << 16);
    U16 lb = bf16_rne(hv - hf);
    hh[(size_t)m*DIM + t] = hb;
    ll[(size_t)m*DIM + t] = lb;
}

// ---------------- NMS: MFMA per-point argmin over centroids ----------------
__global__ __launch_bounds__(256) void argminMK(
    const U16* __restrict__ Ph, const U16* __restrict__ Pl,
    const U16* __restrict__ Ch, const U16* __restrict__ Cl,
    float* __restrict__ aval, int* __restrict__ aidx)
{
    const int tid = threadIdx.x;
    const int lane = tid & 63, wid = tid >> 6;
    const int wr = wid & 1, wc = wid >> 1;
    const int P  = blockIdx.x * 128;
    const int ms = blockIdx.y;
    const int M0 = ms * (NPTS / NSPL);

    __shared__ U16 S[4][4096];
    __shared__ float fmv[128][2];
    __shared__ int   fmi[128][2];

    float pv[16];
    int   pm[16];
    #pragma unroll
    for (int s = 0; s < 16; ++s) { pv[s] = 3.4e38f; pm[s] = 0; }

    for (int mt = 0; mt < (NPTS/NSPL)/128; ++mt) {
        const int M = M0 + mt*128;
        f32x4 acc[4][4];
        #pragma unroll
        for (int a = 0; a < 4; ++a)
            #pragma unroll
            for (int b = 0; b < 4; ++b) { f32x4 z = {0.f,0.f,0.f,0.f}; acc[a][b] = z; }

        for (int k0 = 0; k0 < DIM; k0 += 32) {
            __syncthreads();
            #pragma unroll
            for (int h = 0; h < 2; ++h) {
                const int sb   = wid * 128 + h * 64;
                const int slot = sb + lane;
                const int row  = slot & 127, kg = slot >> 7;
                const int col  = k0 + kg * 8;
                glds16(Ph + (size_t)(P + row)*DIM + col, &S[0][(size_t)sb * 8]);
                glds16(Pl + (size_t)(P + row)*DIM + col, &S[1][(size_t)sb * 8]);
                glds16(Ch + (size_t)(M + row)*DIM + col, &S[2][(size_t)sb * 8]);
                glds16(Cl + (size_t)(M + row)*DIM + col, &S[3][(size_t)sb * 8]);
            }
            __syncthreads();
            bf16x8 fah[4], fal[4], fbh[4], fbl[4];
            const int roff = (lane >> 4) * 128 + (lane & 15);
            #pragma unroll
            for (int f = 0; f < 4; ++f) {
                const int sA = roff + wr*64 + f*16;
                const int sB = roff + wc*64 + f*16;
                fah[f] = *(const bf16x8*)&S[0][(size_t)sA * 8];
                fal[f] = *(const bf16x8*)&S[1][(size_t)sA * 8];
                fbh[f] = *(const bf16x8*)&S[2][(size_t)sB * 8];
                fbl[f] = *(const bf16x8*)&S[3][(size_t)sB * 8];
            }
            #pragma unroll
            for (int a = 0; a < 4; ++a)
                #pragma unroll
                for (int b = 0; b < 4; ++b) {
                    acc[a][b] = __builtin_amdgcn_mfma_f32_16x16x32_bf16(fah[a], fbh[b], acc[a][b], 0,0,0);
                    acc[a][b] = __builtin_amdgcn_mfma_f32_16x16x32_bf16(fah[a], fbl[b], acc[a][b], 0,0,0);
                    acc[a][b] = __builtin_amdgcn_mfma_f32_16x16x32_bf16(fal[a], fbh[b], acc[a][b], 0,0,0);
                }
        }
        #pragma unroll
        for (int a = 0; a < 4; ++a)
            #pragma unroll
            for (int i = 0; i < 4; ++i) {
                const int s = a*4 + i;
                #pragma unroll
                for (int b = 0; b < 4; ++b) {
                    float d = 2.0f*(1.0f - acc[a][b][i]);
                    int m = M + wc*64 + b*16 + (lane & 15);
                    if (d < pv[s] || (d == pv[s] && m < pm[s])) { pv[s]=d; pm[s]=m; }
                }
            }
    }
    #pragma unroll
    for (int msk = 1; msk < 16; msk <<= 1)
        #pragma unroll
        for (int s = 0; s < 16; ++s) {
            float v2 = __shfl_xor(pv[s], msk, 64);
            int   m2 = __shfl_xor(pm[s], msk, 64);
            if (v2 < pv[s] || (v2 == pv[s] && m2 < pm[s])) { pv[s]=v2; pm[s]=m2; }
        }
    if ((lane & 15) == 0) {
        #pragma unroll
        for (int a = 0; a < 4; ++a)
            #pragma unroll
            for (int i = 0; i < 4; ++i) {
                int row = wr*64 + a*16 + (lane>>4)*4 + i;
                fmv[row][wc] = pv[a*4+i];
                fmi[row][wc] = pm[a*4+i];
            }
    }
    __syncthreads();
    if (tid < 128) {
        float v = fmv[tid][0]; int m = fmi[tid][0];
        float v1 = fmv[tid][1]; int m1 = fmi[tid][1];
        if (v1 < v || (v1 == v && m1 < m)) { v=v1; m=m1; }
        aval[(size_t)ms*NPTS + P + tid] = v;
        aidx[(size_t)ms*NPTS + P + tid] = m;
    }
}

__global__ void acombineK(const float* __restrict__ aval, const int* __restrict__ aidx,
                          int* __restrict__ counts)
{
    int p = blockIdx.x*256 + threadIdx.x;
    float bv = 3.4e38f; int bm = 1<<30;
    for (int s = 0; s < NSPL; ++s) {
        float v = aval[(size_t)s*NPTS + p]; int m = aidx[(size_t)s*NPTS + p];
        if (v < bv || (v == bv && m < bm)) { bv=v; bm=m; }
    }
    atomicAdd(&counts[bm], 1);
}

// ---------------- NMS: MFMA per-centroid argmax of close*counts ----------------
__global__ __launch_bounds__(256) void ccMK(
    const U16* __restrict__ Ch, const U16* __restrict__ Cl,
    const int* __restrict__ counts, const float* __restrict__ sigma,
    float* __restrict__ cval, int* __restrict__ cidx)
{
    const int tid = threadIdx.x;
    const int lane = tid & 63, wid = tid >> 6;
    const int wr = wid & 1, wc = wid >> 1;
    const int Mrow = blockIdx.x * 128;
    const int js   = blockIdx.y;
    const int J0   = js * (NPTS / NSPL);
    const float bw = *sigma;

    __shared__ U16 S[4][4096];
    __shared__ float gmv[128][2];
    __shared__ int   gmi[128][2];
    __shared__ float scnt[128];

    float mvv[16];
    int   mjj[16];
    #pragma unroll
    for (int s = 0; s < 16; ++s) { mvv[s] = -1.f; mjj[s] = 1<<30; }

    for (int jt = 0; jt < (NPTS/NSPL)/128; ++jt) {
        const int J = J0 + jt*128;
        __syncthreads();
        if (tid < 128) scnt[tid] = (float)counts[J + tid];
        f32x4 acc[4][4];
        #pragma unroll
        for (int a = 0; a < 4; ++a)
            #pragma unroll
            for (int b = 0; b < 4; ++b) { f32x4 z = {0.f,0.f,0.f,0.f}; acc[a][b] = z; }

        for (int k0 = 0; k0 < DIM; k0 += 32) {
            __syncthreads();
            #pragma unroll
            for (int h = 0; h < 2; ++h) {
                const int sb   = wid * 128 + h * 64;
                const int slot = sb + lane;
                const int row  = slot & 127, kg = slot >> 7;
                const int col  = k0 + kg * 8;
                glds16(Ch + (size_t)(Mrow + row)*DIM + col, &S[0][(size_t)sb * 8]);
                glds16(Cl + (size_t)(Mrow + row)*DIM + col, &S[1][(size_t)sb * 8]);
                glds16(Ch + (size_t)(J + row)*DIM + col,    &S[2][(size_t)sb * 8]);
                glds16(Cl + (size_t)(J + row)*DIM + col,    &S[3][(size_t)sb * 8]);
            }
            __syncthreads();
            bf16x8 fah[4], fal[4], fbh[4], fbl[4];
            const int roff = (lane >> 4) * 128 + (lane & 15);
            #pragma unroll
            for (int f = 0; f < 4; ++f) {
                const int sA = roff + wr*64 + f*16;
                const int sB = roff + wc*64 + f*16;
                fah[f] = *(const bf16x8*)&S[0][(size_t)sA * 8];
                fal[f] = *(const bf16x8*)&S[1][(size_t)sA * 8];
                fbh[f] = *(const bf16x8*)&S[2][(size_t)sB * 8];
                fbl[f] = *(const bf16x8*)&S[3][(size_t)sB * 8];
            }
            #pragma unroll
            for (int a = 0; a < 4; ++a)
                #pragma unroll
                for (int b = 0; b < 4; ++b) {
                    acc[a][b] = __builtin_amdgcn_mfma_f32_16x16x32_bf16(fah[a], fbh[b], acc[a][b], 0,0,0);
                    acc[a][b] = __builtin_amdgcn_mfma_f32_16x16x32_bf16(fah[a], fbl[b], acc[a][b], 0,0,0);
                    acc[a][b] = __builtin_amdgcn_mfma_f32_16x16x32_bf16(fal[a], fbh[b], acc[a][b], 0,0,0);
                }
        }
        #pragma unroll
        for (int a = 0; a < 4; ++a)
            #pragma unroll
            for (int i = 0; i < 4; ++i) {
                const int s = a*4 + i;
                #pragma unroll
                for (int b = 0; b < 4; ++b) {
                    float d = 2.0f*(1.0f - acc[a][b][i]);
                    int jl = wc*64 + b*16 + (lane & 15);
                    float val = (d < bw) ? scnt[jl] : 0.0f;
                    int j = J + jl;
                    if (val > mvv[s] || (val == mvv[s] && j < mjj[s])) { mvv[s]=val; mjj[s]=j; }
                }
            }
    }
    #pragma unroll
    for (int msk = 1; msk < 16; msk <<= 1)
        #pragma unroll
        for (int s = 0; s < 16; ++s) {
            float v2 = __shfl_xor(mvv[s], msk, 64);
            int   j2 = __shfl_xor(mjj[s], msk, 64);
            if (v2 > mvv[s] || (v2 == mvv[s] && j2 < mjj[s])) { mvv[s]=v2; mjj[s]=j2; }
        }
    if ((lane & 15) == 0) {
        #pragma unroll
        for (int a = 0; a < 4; ++a)
            #pragma unroll
            for (int i = 0; i < 4; ++i) {
                int row = wr*64 + a*16 + (lane>>4)*4 + i;
                gmv[row][wc] = mvv[a*4+i];
                gmi[row][wc] = mjj[a*4+i];
            }
    }
    __syncthreads();
    if (tid < 128) {
        float v = gmv[tid][0]; int j = gmi[tid][0];
        float v1 = gmv[tid][1]; int j1 = gmi[tid][1];
        if (v1 > v || (v1 == v && j1 < j)) { v=v1; j=j1; }
        cval[(size_t)js*NPTS + Mrow + tid] = v;
        cidx[(size_t)js*NPTS + Mrow + tid] = j;
    }
}

__global__ void ccombineK(const float* __restrict__ cval, const int* __restrict__ cidx,
                          const int* __restrict__ counts, int* __restrict__ keep)
{
    int m = blockIdx.x*256 + threadIdx.x;
    float bv = -1.0f; int bj = 1<<30;
    for (int s = 0; s < NSPL; ++s) {
        float v = cval[(size_t)s*NPTS + m]; int j = cidx[(size_t)s*NPTS + m];
        if (v > bv || (v == bv && j < bj)) { bv=v; bj=j; }
    }
    if (counts[m] > 0) atomicOr(&keep[bj], 1);
}

__global__ void keepwriteK(const int* __restrict__ keep, float* __restrict__ out)
{
    int i = blockIdx.x*256 + threadIdx.x;
    out[(size_t)NPTS*DIM + i] = keep[i] ? 1.0f : 0.0f;
}

// ---------------- host ----------------
extern "C" void kernel_launch(void* const* d_in, const int* in_sizes, int n_in,
                              void* d_out, int out_size, void* d_ws, size_t ws_size,
                              hipStream_t stream)
{
    const float* x     = (const float*)d_in[0];
    const float* sigma = (const float*)d_in[1];
    float* out = (float*)d_out;

    const size_t ND4 = (size_t)NPTS * DIM * 4;   // 4 MB
    const size_t NDu = (size_t)NPTS * DIM * 2;   // 2 MB

    const int spls[] = {8, 4, 2};
    int SPL = 2;
    size_t o_xh=0,o_xl=0,o_xth=0,o_xtl=0,o_chh=0,o_chl=0,o_c0=0,o_c1=0,o_c2=0,
           o_cnum=0,o_psum=0,o_aval=0,o_aidx=0,o_cval=0,o_cidx=0,
           o_counts=0,o_keep=0,o_done=0,o_shift=0,o_acc=0;

    for (int ci = 0; ci < 3; ++ci) {
        int spl = spls[ci];
        size_t off = 0;
        auto take = [&](size_t nb) { size_t a = off; off += (nb + 255) & ~(size_t)255; return a; };
        o_xh  = take(NDu);  o_xl  = take(NDu);
        o_xth = take(NDu);  o_xtl = take(NDu);
        o_chh = take(NDu);  o_chl = take(NDu);
        o_c0  = take(ND4);  o_c1  = take(ND4);  o_c2 = take(ND4);
        o_cnum = take((size_t)spl * ND4);
        o_psum = take((size_t)spl * NPTS * 4);
        o_aval = take((size_t)NSPL*NPTS*4); o_aidx = take((size_t)NSPL*NPTS*4);
        o_cval = take((size_t)NSPL*NPTS*4); o_cidx = take((size_t)NSPL*NPTS*4);
        o_counts = take((size_t)NPTS*4);    o_keep = take((size_t)NPTS*4);
        o_done = take(256); o_shift = take(256); o_acc = take(256);
        SPL = spl;
        if (off <= ws_size) break;
    }
    const int KLEN = NPTS / SPL;

    char* W = (char*)d_ws;
    U16* xh  = (U16*)(W + o_xh);   U16* xl  = (U16*)(W + o_xl);
    U16* xth = (U16*)(W + o_xth);  U16* xtl = (U16*)(W + o_xtl);
    U16* chh = (U16*)(W + o_chh);  U16* chl = (U16*)(W + o_chl);
    float* cb[3] = { (float*)(W + o_c0), (float*)(W + o_c1), (float*)(W + o_c2) };
    float* cnum = (float*)(W + o_cnum);
    float* psum = (float*)(W + o_psum);
    float* aval = (float*)(W + o_aval); int* aidx = (int*)(W + o_aidx);
    float* cval = (float*)(W + o_cval); int* cidx = (int*)(W + o_cidx);
    int* counts = (int*)(W + o_counts); int* keep = (int*)(W + o_keep);
    int* done   = (int*)(W + o_done);   int* shiftb = (int*)(W + o_shift);
    int* acc    = (int*)(W + o_acc);

    initK  <<<dim3(16), dim3(256), 0, stream>>>(counts, keep, done, shiftb, acc);
    normxK <<<dim3(NPTS), dim3(256), 0, stream>>>(x, cb[0], xh, xl);
    transpK<<<dim3(128, 8), dim3(256), 0, stream>>>(x, xth, xtl);

    for (int it = 0; it < MAX_ITERS; ++it) {
        const U16* ah = (it == 0) ? xh : chh;
        const U16* al = (it == 0) ? xl : chl;
        const int cur = 1 + (it & 1);
        const int prv = (it == 0) ? 0 : 1 + ((it - 1) & 1);
        fusedK<<<dim3(SPL, NPTS/64), dim3(256), 0, stream>>>(
            ah, al, xh, xl, xth, xtl, cnum, psum, done, sigma, KLEN);
        reduceK<<<dim3(NPTS), dim3(256), 0, stream>>>(
            psum, cnum, cb[prv], cb[cur], chh, chl, done, shiftb, SPL);
        flagK<<<dim3(1), dim3(1), 0, stream>>>(done, shiftb, acc, cur);
    }

    finalK    <<<dim3(NPTS), dim3(256), 0, stream>>>(cb[0], cb[1], cb[2], acc, out);
    normfinalK<<<dim3(NPTS), dim3(256), 0, stream>>>(cb[0], cb[1], cb[2], acc, chh, chl);

    argminMK<<<dim3(NPTS/128, NSPL), dim3(256), 0, stream>>>(xh, xl, chh, chl, aval, aidx);
    acombineK<<<dim3(NPTS/256), dim3(256), 0, stream>>>(aval, aidx, counts);
    ccMK    <<<dim3(NPTS/128, NSPL), dim3(256), 0, stream>>>(chh, chl, counts, sigma, cval, cidx);
    ccombineK<<<dim3(NPTS/256), dim3(256), 0, stream>>>(cval, cidx, counts, keep);
    keepwriteK<<<dim3(NPTS/256), dim3(256), 0, stream>>>(keep, out);
}

// Round 15
// 1504.606 us; speedup vs baseline: 1.3713x; 1.2235x over previous
//
#include <hip/hip_runtime.h>
#include <math.h>

#define NPTS 4096
#define DIM  256
#define MAX_ITERS 10
#define EPSN 1e-8f
#define NSPL 16   // splits for NMS kernels

typedef __bf16 bf16x8 __attribute__((ext_vector_type(8)));
typedef float  f32x4  __attribute__((ext_vector_type(4)));
typedef unsigned short u16x8 __attribute__((ext_vector_type(8)));
typedef unsigned short u16x4 __attribute__((ext_vector_type(4)));
typedef unsigned short U16;

__device__ __forceinline__ U16 bf16_rne(float f) {
    unsigned int u = __float_as_uint(f);
    u += 0x7FFFu + ((u >> 16) & 1u);
    return (U16)(u >> 16);
}

__device__ __forceinline__ void glds16(const void* g, void* l) {
    __builtin_amdgcn_global_load_lds(
        (const __attribute__((address_space(1))) unsigned int*)g,
        (__attribute__((address_space(3))) unsigned int*)l,
        16, 0, 0);
}

// ---------------- prep ----------------
__global__ void initK(int* counts, int* keep, int* done, int* shiftb, int* acc) {
    int i = blockIdx.x * 256 + threadIdx.x;
    if (i < NPTS) { counts[i] = 0; keep[i] = 0; }
    if (i == 0) { *done = 0; *shiftb = 0; *acc = 0; }
}

// x -> c0 (copy), xhat hi/lo splits
__global__ void normxK(const float* __restrict__ x, float* __restrict__ c0,
                       U16* __restrict__ xh, U16* __restrict__ xl) {
    int m = blockIdx.x, t = threadIdx.x;
    float v = x[(size_t)m*DIM + t];
    __shared__ float red[256];
    red[t] = v*v; __syncthreads();
    for (int s = 128; s > 0; s >>= 1) { if (t < s) red[t] += red[t+s]; __syncthreads(); }
    float rn = 1.0f / fmaxf(sqrtf(red[0]), EPSN);
    float hv = v*rn;
    U16 hb = bf16_rne(hv);
    float hf = __uint_as_float((unsigned)hb << 16);
    U16 lb = bf16_rne(hv - hf);
    c0[(size_t)m*DIM + t] = v;
    xh[(size_t)m*DIM + t] = hb;
    xl[(size_t)m*DIM + t] = lb;
}

// x^T split: Xt[d][p] = x[p][d] as bf16 hi/lo
__global__ void transpK(const float* __restrict__ x, U16* __restrict__ Xth, U16* __restrict__ Xtl) {
    int bm = blockIdx.x, bd = blockIdx.y;
    int t = threadIdx.x;
    __shared__ float sh[32][33];
    int r = t >> 3, cq = (t & 7) * 4;
    float4 v = *(const float4*)&x[(size_t)(bm*32 + r)*DIM + bd*32 + cq];
    sh[r][cq] = v.x; sh[r][cq+1] = v.y; sh[r][cq+2] = v.z; sh[r][cq+3] = v.w;
    __syncthreads();
    int dd = t >> 3, mq = (t & 7) * 4;
    u16x4 h4, l4;
    #pragma unroll
    for (int j = 0; j < 4; ++j) {
        float f = sh[mq + j][dd];
        U16 hb = bf16_rne(f);
        h4[j] = hb;
        l4[j] = bf16_rne(f - __uint_as_float((unsigned)hb << 16));
    }
    size_t off = (size_t)(bd*32 + dd)*NPTS + bm*32 + mq;
    *(u16x4*)&Xth[off] = h4;
    *(u16x4*)&Xtl[off] = l4;
}

// ---------------- fusedK: one mean-shift iteration slice ----------------
// R14 = R10 + j-tile 256 (was 128): barriers halve to 8/block, each phase is
// a 384-MFMA run (longer ILP window between full-drain barriers at 1
// wave/SIMD).  Regs ~230 <= 256 one-wave budget (R5 proved 252 OK, no spill).
// Occupancy path abandoned: R12/R13 proved 2 waves/SIMD needs total<=128
// regs, which costs more density/spill than TLP gains.
// LDS 131 KB dynamic: chat hi+lo [32kb][64row][8] (64K) + W hi/lo [64][264]
// (67.6K) + psw (1K).  Grid (SPL=4, 64) = 256 blocks = 1/CU.
#define WPADJ 264
__global__ __launch_bounds__(256, 1) void fusedK(
    const U16* __restrict__ chh, const U16* __restrict__ chl,
    const U16* __restrict__ xh,  const U16* __restrict__ xl,
    const U16* __restrict__ xth, const U16* __restrict__ xtl,
    float* __restrict__ cnum, float* __restrict__ psum,
    const int* __restrict__ done, const float* __restrict__ sigma,
    int KLEN)
{
    extern __shared__ char smraw[];
    U16* ChAh = (U16*)smraw;              // [32][64][8] bf16 hi  (32 KB)
    U16* ChAl = ChAh + 16384;             // [32][64][8] bf16 lo  (32 KB)
    U16* WhL  = ChAl + 16384;             // [64][264]            (33.8 KB)
    U16* WlL  = WhL + 64*WPADJ;           // [64][264]            (33.8 KB)
    float* psw = (float*)(WlL + 64*WPADJ); // [4][64]             (1 KB)

    if (*done) return;
    const int tid  = threadIdx.x;
    const int lane = tid & 63, wq = tid >> 6;      // wq in 0..3
    const int l15  = lane & 15, lg = lane >> 4;
    const int slice = blockIdx.x;
    const int mblk  = blockIdx.y * 64;
    const int j0g  = slice * KLEN;

    const float ig = 1.0f / (2.0f * (*sigma) * (*sigma));

    // ---- stage chat tile (hi+lo) into LDS, slot layout [kb][row][8] ----
    {
        const int r = mblk + lane;
        #pragma unroll
        for (int q = 0; q < 8; ++q) {
            const int kb = wq*8 + q;   // wave-uniform dest; HW scatters +lane*16
            glds16(chh + (size_t)r*DIM + kb*8, ChAh + (size_t)kb*512);
            glds16(chl + (size_t)r*DIM + kb*8, ChAl + (size_t)kb*512);
        }
    }
    __syncthreads();

    f32x4 acc2[4][4];
    #pragma unroll
    for (int a = 0; a < 4; ++a)
        #pragma unroll
        for (int b = 0; b < 4; ++b) { f32x4 z = {0.f,0.f,0.f,0.f}; acc2[a][b] = z; }
    float rs[4][4];
    #pragma unroll
    for (int a = 0; a < 4; ++a)
        #pragma unroll
        for (int i = 0; i < 4; ++i) rs[a][i] = 0.f;

    const int NJT = KLEN / 256;
    for (int jt = 0; jt < NJT; ++jt) {
        const int jb = j0g + jt * 256;

        // ---- phase A: S(64x256) = chat_tile . xhat_jtile^T ----
        // A-frags from LDS; wave wq owns 64 j-cols (4 b-frags).
        f32x4 acc1[4][4];
        #pragma unroll
        for (int a = 0; a < 4; ++a)
            #pragma unroll
            for (int b = 0; b < 4; ++b) { f32x4 z = {0.f,0.f,0.f,0.f}; acc1[a][b] = z; }

        #pragma unroll
        for (int ks = 0; ks < 8; ++ks) {
            const int k0 = ks * 32 + lg * 8;
            const int kb = ks*4 + lg;
            bf16x8 ah[4], al[4], bh[4], bl[4];
            #pragma unroll
            for (int a = 0; a < 4; ++a) {
                const int slot = kb*64 + a*16 + l15;
                ah[a] = *(const bf16x8*)&ChAh[(size_t)slot * 8];
                al[a] = *(const bf16x8*)&ChAl[(size_t)slot * 8];
            }
            #pragma unroll
            for (int b = 0; b < 4; ++b) {
                size_t off = (size_t)(jb + wq*64 + b*16 + l15)*DIM + k0;
                bh[b] = *(const bf16x8*)(xh + off);
                bl[b] = *(const bf16x8*)(xl + off);
            }
            #pragma unroll
            for (int a = 0; a < 4; ++a)
                #pragma unroll
                for (int b = 0; b < 4; ++b) {
                    acc1[a][b] = __builtin_amdgcn_mfma_f32_16x16x32_bf16(ah[a], bh[b], acc1[a][b], 0,0,0);
                    acc1[a][b] = __builtin_amdgcn_mfma_f32_16x16x32_bf16(ah[a], bl[b], acc1[a][b], 0,0,0);
                    acc1[a][b] = __builtin_amdgcn_mfma_f32_16x16x32_bf16(al[a], bh[b], acc1[a][b], 0,0,0);
                }
        }

        // ---- epilogue: w = exp(2(s-1)ig), split, stash in LDS ----
        __syncthreads();   // previous tile's phase-B readers must be done
        #pragma unroll
        for (int a = 0; a < 4; ++a)
            #pragma unroll
            for (int b = 0; b < 4; ++b)
                #pragma unroll
                for (int i = 0; i < 4; ++i) {
                    float w = __expf(2.0f * (acc1[a][b][i] - 1.0f) * ig);
                    U16 hb = bf16_rne(w);
                    float hf = __uint_as_float((unsigned)hb << 16);
                    U16 lb = bf16_rne(w - hf);
                    int m = a*16 + lg*4 + i;
                    int j = wq*64 + b*16 + l15;
                    WhL[m*WPADJ + j] = hb;
                    WlL[m*WPADJ + j] = lb;
                    rs[a][i] += w;
                }
        __syncthreads();

        // ---- phase B: acc2 += W(64x256) . X_jtile(256x256) ----
        #pragma unroll
        for (int ks = 0; ks < 8; ++ks) {
            bf16x8 wh[4], wl[4], xbh[4], xbl[4];
            const int jl = ks*32 + lg*8;
            #pragma unroll
            for (int a = 0; a < 4; ++a) {
                int m = a*16 + l15;
                wh[a] = *(const bf16x8*)&WhL[m*WPADJ + jl];
                wl[a] = *(const bf16x8*)&WlL[m*WPADJ + jl];
            }
            #pragma unroll
            for (int b = 0; b < 4; ++b) {
                size_t off = (size_t)(wq*64 + b*16 + l15)*NPTS + jb + jl;
                xbh[b] = *(const bf16x8*)(xth + off);
                xbl[b] = *(const bf16x8*)(xtl + off);
            }
            #pragma unroll
            for (int a = 0; a < 4; ++a)
                #pragma unroll
                for (int b = 0; b < 4; ++b) {
                    acc2[a][b] = __builtin_amdgcn_mfma_f32_16x16x32_bf16(wh[a], xbh[b], acc2[a][b], 0,0,0);
                    acc2[a][b] = __builtin_amdgcn_mfma_f32_16x16x32_bf16(wh[a], xbl[b], acc2[a][b], 0,0,0);
                    acc2[a][b] = __builtin_amdgcn_mfma_f32_16x16x32_bf16(wl[a], xbh[b], acc2[a][b], 0,0,0);
                }
        }
    }

    // ---- row sums -> psum[slice][m] ----
    #pragma unroll
    for (int msk = 1; msk < 16; msk <<= 1)
        #pragma unroll
        for (int a = 0; a < 4; ++a)
            #pragma unroll
            for (int i = 0; i < 4; ++i)
                rs[a][i] += __shfl_xor(rs[a][i], msk, 64);
    __syncthreads();
    if (l15 == 0) {
        #pragma unroll
        for (int a = 0; a < 4; ++a)
            #pragma unroll
            for (int i = 0; i < 4; ++i)
                psw[wq*64 + a*16 + lg*4 + i] = rs[a][i];
    }
    __syncthreads();
    if (tid < 64)
        psum[(size_t)slice*NPTS + mblk + tid] =
            psw[0*64+tid] + psw[1*64+tid] + psw[2*64+tid] + psw[3*64+tid];

    // ---- store cnum[slice] ----
    #pragma unroll
    for (int a = 0; a < 4; ++a)
        #pragma unroll
        for (int b = 0; b < 4; ++b)
            #pragma unroll
            for (int i = 0; i < 4; ++i) {
                int m = mblk + a*16 + lg*4 + i;
                int d = wq*64 + b*16 + l15;
                cnum[((size_t)slice*NPTS + m)*DIM + d] = acc2[a][b][i];
            }
}

// ---------------- reduce: cnew = cnum/rowsum, shift, normalize+split ----------------
__global__ void reduceK(const float* __restrict__ psum, const float* __restrict__ cnum,
                        const float* __restrict__ cprev, float* __restrict__ ccur,
                        U16* __restrict__ chh, U16* __restrict__ chl,
                        const int* __restrict__ done, int* __restrict__ shiftb, int spl)
{
    if (*done) return;
    int m = blockIdx.x, t = threadIdx.x;
    float rowsum = 0.f;
    for (int s = 0; s < spl; ++s) rowsum += psum[(size_t)s*NPTS + m];
    float num = 0.f;
    for (int s = 0; s < spl; ++s) num += cnum[((size_t)s*NPTS + m)*DIM + t];
    float cn = num / rowsum;
    ccur[(size_t)m*DIM + t] = cn;
    float d = cn - cprev[(size_t)m*DIM + t];
    __shared__ float redd[256], redn[256];
    redd[t] = d*d; redn[t] = cn*cn;
    __syncthreads();
    for (int st = 128; st > 0; st >>= 1) {
        if (t < st) { redd[t] += redd[t+st]; redn[t] += redn[t+st]; }
        __syncthreads();
    }
    if (t == 0) atomicMax(shiftb, __float_as_int(sqrtf(redd[0])));
    float rn = 1.0f / fmaxf(sqrtf(redn[0]), EPSN);
    float hv = cn * rn;
    U16 hb = bf16_rne(hv);
    float hf = __uint_as_float((unsigned)hb << 16);
    U16 lb = bf16_rne(hv - hf);
    chh[(size_t)m*DIM + t] = hb;
    chl[(size_t)m*DIM + t] = lb;
}

// accept/reject: on accept record buffer index, on reject freeze
__global__ void flagK(int* done, int* shiftb, int* acc, int curidx) {
    if (!*done) {
        float sh = __int_as_float(*shiftb);
        if (sh < 1e-5f) *done = 1;
        else *acc = curidx;
    }
    *shiftb = 0;
}

// out[0:N*D] = accepted centroid buffer
__global__ void finalK(const float* __restrict__ p0, const float* __restrict__ p1,
                       const float* __restrict__ p2, const int* __restrict__ acc,
                       float* __restrict__ out) {
    int i = blockIdx.x*256 + threadIdx.x;
    const float* p = (*acc == 0) ? p0 : ((*acc == 1) ? p1 : p2);
    out[i] = p[i];
}

// normalize accepted centroids -> hi/lo splits (for NMS)
__global__ void normfinalK(const float* __restrict__ p0, const float* __restrict__ p1,
                           const float* __restrict__ p2, const int* __restrict__ acc,
                           U16* __restrict__ hh, U16* __restrict__ ll) {
    int m = blockIdx.x, t = threadIdx.x;
    const float* p = (*acc == 0) ? p0 : ((*acc == 1) ? p1 : p2);
    float v = p[(size_t)m*DIM + t];
    __shared__ float red[256];
    red[t] = v*v; __syncthreads();
    for (int s = 128; s > 0; s >>= 1) { if (t < s) red[t] += red[t+s]; __syncthreads(); }
    float rn = 1.0f / fmaxf(sqrtf(red[0]), EPSN);
    float hv = v*rn;
    U16 hb = bf16_rne(hv);
    float hf = __uint_as_float((unsigned)hb << 16);
    U16 lb = bf16_rne(hv - hf);
    hh[(size_t)m*DIM + t] = hb;
    ll[(size_t)m*DIM + t] = lb;
}

// ---------------- NMS: MFMA per-point argmin over centroids ----------------
__global__ __launch_bounds__(256) void argminMK(
    const U16* __restrict__ Ph, const U16* __restrict__ Pl,
    const U16* __restrict__ Ch, const U16* __restrict__ Cl,
    float* __restrict__ aval, int* __restrict__ aidx)
{
    const int tid = threadIdx.x;
    const int lane = tid & 63, wid = tid >> 6;
    const int wr = wid & 1, wc = wid >> 1;
    const int P  = blockIdx.x * 128;
    const int ms = blockIdx.y;
    const int M0 = ms * (NPTS / NSPL);

    __shared__ U16 S[4][4096];
    __shared__ float fmv[128][2];
    __shared__ int   fmi[128][2];

    float pv[16];
    int   pm[16];
    #pragma unroll
    for (int s = 0; s < 16; ++s) { pv[s] = 3.4e38f; pm[s] = 0; }

    for (int mt = 0; mt < (NPTS/NSPL)/128; ++mt) {
        const int M = M0 + mt*128;
        f32x4 acc[4][4];
        #pragma unroll
        for (int a = 0; a < 4; ++a)
            #pragma unroll
            for (int b = 0; b < 4; ++b) { f32x4 z = {0.f,0.f,0.f,0.f}; acc[a][b] = z; }

        for (int k0 = 0; k0 < DIM; k0 += 32) {
            __syncthreads();
            #pragma unroll
            for (int h = 0; h < 2; ++h) {
                const int sb   = wid * 128 + h * 64;
                const int slot = sb + lane;
                const int row  = slot & 127, kg = slot >> 7;
                const int col  = k0 + kg * 8;
                glds16(Ph + (size_t)(P + row)*DIM + col, &S[0][(size_t)sb * 8]);
                glds16(Pl + (size_t)(P + row)*DIM + col, &S[1][(size_t)sb * 8]);
                glds16(Ch + (size_t)(M + row)*DIM + col, &S[2][(size_t)sb * 8]);
                glds16(Cl + (size_t)(M + row)*DIM + col, &S[3][(size_t)sb * 8]);
            }
            __syncthreads();
            bf16x8 fah[4], fal[4], fbh[4], fbl[4];
            const int roff = (lane >> 4) * 128 + (lane & 15);
            #pragma unroll
            for (int f = 0; f < 4; ++f) {
                const int sA = roff + wr*64 + f*16;
                const int sB = roff + wc*64 + f*16;
                fah[f] = *(const bf16x8*)&S[0][(size_t)sA * 8];
                fal[f] = *(const bf16x8*)&S[1][(size_t)sA * 8];
                fbh[f] = *(const bf16x8*)&S[2][(size_t)sB * 8];
                fbl[f] = *(const bf16x8*)&S[3][(size_t)sB * 8];
            }
            #pragma unroll
            for (int a = 0; a < 4; ++a)
                #pragma unroll
                for (int b = 0; b < 4; ++b) {
                    acc[a][b] = __builtin_amdgcn_mfma_f32_16x16x32_bf16(fah[a], fbh[b], acc[a][b], 0,0,0);
                    acc[a][b] = __builtin_amdgcn_mfma_f32_16x16x32_bf16(fah[a], fbl[b], acc[a][b], 0,0,0);
                    acc[a][b] = __builtin_amdgcn_mfma_f32_16x16x32_bf16(fal[a], fbh[b], acc[a][b], 0,0,0);
                }
        }
        #pragma unroll
        for (int a = 0; a < 4; ++a)
            #pragma unroll
            for (int i = 0; i < 4; ++i) {
                const int s = a*4 + i;
                #pragma unroll
                for (int b = 0; b < 4; ++b) {
                    float d = 2.0f*(1.0f - acc[a][b][i]);
                    int m = M + wc*64 + b*16 + (lane & 15);
                    if (d < pv[s] || (d == pv[s] && m < pm[s])) { pv[s]=d; pm[s]=m; }
                }
            }
    }
    #pragma unroll
    for (int msk = 1; msk < 16; msk <<= 1)
        #pragma unroll
        for (int s = 0; s < 16; ++s) {
            float v2 = __shfl_xor(pv[s], msk, 64);
            int   m2 = __shfl_xor(pm[s], msk, 64);
            if (v2 < pv[s] || (v2 == pv[s] && m2 < pm[s])) { pv[s]=v2; pm[s]=m2; }
        }
    if ((lane & 15) == 0) {
        #pragma unroll
        for (int a = 0; a < 4; ++a)
            #pragma unroll
            for (int i = 0; i < 4; ++i) {
                int row = wr*64 + a*16 + (lane>>4)*4 + i;
                fmv[row][wc] = pv[a*4+i];
                fmi[row][wc] = pm[a*4+i];
            }
    }
    __syncthreads();
    if (tid < 128) {
        float v = fmv[tid][0]; int m = fmi[tid][0];
        float v1 = fmv[tid][1]; int m1 = fmi[tid][1];
        if (v1 < v || (v1 == v && m1 < m)) { v=v1; m=m1; }
        aval[(size_t)ms*NPTS + P + tid] = v;
        aidx[(size_t)ms*NPTS + P + tid] = m;
    }
}

__global__ void acombineK(const float* __restrict__ aval, const int* __restrict__ aidx,
                          int* __restrict__ counts)
{
    int p = blockIdx.x*256 + threadIdx.x;
    float bv = 3.4e38f; int bm = 1<<30;
    for (int s = 0; s < NSPL; ++s) {
        float v = aval[(size_t)s*NPTS + p]; int m = aidx[(size_t)s*NPTS + p];
        if (v < bv || (v == bv && m < bm)) { bv=v; bm=m; }
    }
    atomicAdd(&counts[bm], 1);
}

// ---------------- NMS: MFMA per-centroid argmax of close*counts ----------------
__global__ __launch_bounds__(256) void ccMK(
    const U16* __restrict__ Ch, const U16* __restrict__ Cl,
    const int* __restrict__ counts, const float* __restrict__ sigma,
    float* __restrict__ cval, int* __restrict__ cidx)
{
    const int tid = threadIdx.x;
    const int lane = tid & 63, wid = tid >> 6;
    const int wr = wid & 1, wc = wid >> 1;
    const int Mrow = blockIdx.x * 128;
    const int js   = blockIdx.y;
    const int J0   = js * (NPTS / NSPL);
    const float bw = *sigma;

    __shared__ U16 S[4][4096];
    __shared__ float gmv[128][2];
    __shared__ int   gmi[128][2];
    __shared__ float scnt[128];

    float mvv[16];
    int   mjj[16];
    #pragma unroll
    for (int s = 0; s < 16; ++s) { mvv[s] = -1.f; mjj[s] = 1<<30; }

    for (int jt = 0; jt < (NPTS/NSPL)/128; ++jt) {
        const int J = J0 + jt*128;
        __syncthreads();
        if (tid < 128) scnt[tid] = (float)counts[J + tid];
        f32x4 acc[4][4];
        #pragma unroll
        for (int a = 0; a < 4; ++a)
            #pragma unroll
            for (int b = 0; b < 4; ++b) { f32x4 z = {0.f,0.f,0.f,0.f}; acc[a][b] = z; }

        for (int k0 = 0; k0 < DIM; k0 += 32) {
            __syncthreads();
            #pragma unroll
            for (int h = 0; h < 2; ++h) {
                const int sb   = wid * 128 + h * 64;
                const int slot = sb + lane;
                const int row  = slot & 127, kg = slot >> 7;
                const int col  = k0 + kg * 8;
                glds16(Ch + (size_t)(Mrow + row)*DIM + col, &S[0][(size_t)sb * 8]);
                glds16(Cl + (size_t)(Mrow + row)*DIM + col, &S[1][(size_t)sb * 8]);
                glds16(Ch + (size_t)(J + row)*DIM + col,    &S[2][(size_t)sb * 8]);
                glds16(Cl + (size_t)(J + row)*DIM + col,    &S[3][(size_t)sb * 8]);
            }
            __syncthreads();
            bf16x8 fah[4], fal[4], fbh[4], fbl[4];
            const int roff = (lane >> 4) * 128 + (lane & 15);
            #pragma unroll
            for (int f = 0; f < 4; ++f) {
                const int sA = roff + wr*64 + f*16;
                const int sB = roff + wc*64 + f*16;
                fah[f] = *(const bf16x8*)&S[0][(size_t)sA * 8];
                fal[f] = *(const bf16x8*)&S[1][(size_t)sA * 8];
                fbh[f] = *(const bf16x8*)&S[2][(size_t)sB * 8];
                fbl[f] = *(const bf16x8*)&S[3][(size_t)sB * 8];
            }
            #pragma unroll
            for (int a = 0; a < 4; ++a)
                #pragma unroll
                for (int b = 0; b < 4; ++b) {
                    acc[a][b] = __builtin_amdgcn_mfma_f32_16x16x32_bf16(fah[a], fbh[b], acc[a][b], 0,0,0);
                    acc[a][b] = __builtin_amdgcn_mfma_f32_16x16x32_bf16(fah[a], fbl[b], acc[a][b], 0,0,0);
                    acc[a][b] = __builtin_amdgcn_mfma_f32_16x16x32_bf16(fal[a], fbh[b], acc[a][b], 0,0,0);
                }
        }
        #pragma unroll
        for (int a = 0; a < 4; ++a)
            #pragma unroll
            for (int i = 0; i < 4; ++i) {
                const int s = a*4 + i;
                #pragma unroll
                for (int b = 0; b < 4; ++b) {
                    float d = 2.0f*(1.0f - acc[a][b][i]);
                    int jl = wc*64 + b*16 + (lane & 15);
                    float val = (d < bw) ? scnt[jl] : 0.0f;
                    int j = J + jl;
                    if (val > mvv[s] || (val == mvv[s] && j < mjj[s])) { mvv[s]=val; mjj[s]=j; }
                }
            }
    }
    #pragma unroll
    for (int msk = 1; msk < 16; msk <<= 1)
        #pragma unroll
        for (int s = 0; s < 16; ++s) {
            float v2 = __shfl_xor(mvv[s], msk, 64);
            int   j2 = __shfl_xor(mjj[s], msk, 64);
            if (v2 > mvv[s] || (v2 == mvv[s] && j2 < mjj[s])) { mvv[s]=v2; mjj[s]=j2; }
        }
    if ((lane & 15) == 0) {
        #pragma unroll
        for (int a = 0; a < 4; ++a)
            #pragma unroll
            for (int i = 0; i < 4; ++i) {
                int row = wr*64 + a*16 + (lane>>4)*4 + i;
                gmv[row][wc] = mvv[a*4+i];
                gmi[row][wc] = mjj[a*4+i];
            }
    }
    __syncthreads();
    if (tid < 128) {
        float v = gmv[tid][0]; int j = gmi[tid][0];
        float v1 = gmv[tid][1]; int j1 = gmi[tid][1];
        if (v1 > v || (v1 == v && j1 < j)) { v=v1; j=j1; }
        cval[(size_t)js*NPTS + Mrow + tid] = v;
        cidx[(size_t)js*NPTS + Mrow + tid] = j;
    }
}

__global__ void ccombineK(const float* __restrict__ cval, const int* __restrict__ cidx,
                          const int* __restrict__ counts, int* __restrict__ keep)
{
    int m = blockIdx.x*256 + threadIdx.x;
    float bv = -1.0f; int bj = 1<<30;
    for (int s = 0; s < NSPL; ++s) {
        float v = cval[(size_t)s*NPTS + m]; int j = cidx[(size_t)s*NPTS + m];
        if (v > bv || (v == bv && j < bj)) { bv=v; bj=j; }
    }
    if (counts[m] > 0) atomicOr(&keep[bj], 1);
}

__global__ void keepwriteK(const int* __restrict__ keep, float* __restrict__ out)
{
    int i = blockIdx.x*256 + threadIdx.x;
    out[(size_t)NPTS*DIM + i] = keep[i] ? 1.0f : 0.0f;
}

// ---------------- host ----------------
extern "C" void kernel_launch(void* const* d_in, const int* in_sizes, int n_in,
                              void* d_out, int out_size, void* d_ws, size_t ws_size,
                              hipStream_t stream)
{
    const float* x     = (const float*)d_in[0];
    const float* sigma = (const float*)d_in[1];
    float* out = (float*)d_out;

    const size_t ND4 = (size_t)NPTS * DIM * 4;   // 4 MB
    const size_t NDu = (size_t)NPTS * DIM * 2;   // 2 MB

    const int spls[] = {4, 2, 1};
    int SPL = 1;
    size_t o_xh=0,o_xl=0,o_xth=0,o_xtl=0,o_chh=0,o_chl=0,o_c0=0,o_c1=0,o_c2=0,
           o_cnum=0,o_psum=0,o_aval=0,o_aidx=0,o_cval=0,o_cidx=0,
           o_counts=0,o_keep=0,o_done=0,o_shift=0,o_acc=0;

    for (int ci = 0; ci < 3; ++ci) {
        int spl = spls[ci];
        size_t off = 0;
        auto take = [&](size_t nb) { size_t a = off; off += (nb + 255) & ~(size_t)255; return a; };
        o_xh  = take(NDu);  o_xl  = take(NDu);
        o_xth = take(NDu);  o_xtl = take(NDu);
        o_chh = take(NDu);  o_chl = take(NDu);
        o_c0  = take(ND4);  o_c1  = take(ND4);  o_c2 = take(ND4);
        o_cnum = take((size_t)spl * ND4);
        o_psum = take((size_t)spl * NPTS * 4);
        o_aval = take((size_t)NSPL*NPTS*4); o_aidx = take((size_t)NSPL*NPTS*4);
        o_cval = take((size_t)NSPL*NPTS*4); o_cidx = take((size_t)NSPL*NPTS*4);
        o_counts = take((size_t)NPTS*4);    o_keep = take((size_t)NPTS*4);
        o_done = take(256); o_shift = take(256); o_acc = take(256);
        SPL = spl;
        if (off <= ws_size) break;
    }
    const int KLEN = NPTS / SPL;

    char* W = (char*)d_ws;
    U16* xh  = (U16*)(W + o_xh);   U16* xl  = (U16*)(W + o_xl);
    U16* xth = (U16*)(W + o_xth);  U16* xtl = (U16*)(W + o_xtl);
    U16* chh = (U16*)(W + o_chh);  U16* chl = (U16*)(W + o_chl);
    float* cb[3] = { (float*)(W + o_c0), (float*)(W + o_c1), (float*)(W + o_c2) };
    float* cnum = (float*)(W + o_cnum);
    float* psum = (float*)(W + o_psum);
    float* aval = (float*)(W + o_aval); int* aidx = (int*)(W + o_aidx);
    float* cval = (float*)(W + o_cval); int* cidx = (int*)(W + o_cidx);
    int* counts = (int*)(W + o_counts); int* keep = (int*)(W + o_keep);
    int* done   = (int*)(W + o_done);   int* shiftb = (int*)(W + o_shift);
    int* acc    = (int*)(W + o_acc);

    // dynamic LDS for fusedK: chat 64K + W 67.6K + psw 1K = 132.6 KB
    const int FUSED_LDS = 2*32768 + 2*(64*WPADJ*2) + 4*64*4;   // 134144 B
    (void)hipFuncSetAttribute((const void*)fusedK,
                              hipFuncAttributeMaxDynamicSharedMemorySize, FUSED_LDS);

    initK  <<<dim3(16), dim3(256), 0, stream>>>(counts, keep, done, shiftb, acc);
    normxK <<<dim3(NPTS), dim3(256), 0, stream>>>(x, cb[0], xh, xl);
    transpK<<<dim3(128, 8), dim3(256), 0, stream>>>(x, xth, xtl);

    for (int it = 0; it < MAX_ITERS; ++it) {
        const U16* ah = (it == 0) ? xh : chh;
        const U16* al = (it == 0) ? xl : chl;
        const int cur = 1 + (it & 1);
        const int prv = (it == 0) ? 0 : 1 + ((it - 1) & 1);
        fusedK<<<dim3(SPL, NPTS/64), dim3(256), FUSED_LDS, stream>>>(
            ah, al, xh, xl, xth, xtl, cnum, psum, done, sigma, KLEN);
        reduceK<<<dim3(NPTS), dim3(256), 0, stream>>>(
            psum, cnum, cb[prv], cb[cur], chh, chl, done, shiftb, SPL);
        flagK<<<dim3(1), dim3(1), 0, stream>>>(done, shiftb, acc, cur);
    }

    finalK    <<<dim3(NPTS), dim3(256), 0, stream>>>(cb[0], cb[1], cb[2], acc, out);
    normfinalK<<<dim3(NPTS), dim3(256), 0, stream>>>(cb[0], cb[1], cb[2], acc, chh, chl);

    argminMK<<<dim3(NPTS/128, NSPL), dim3(256), 0, stream>>>(xh, xl, chh, chl, aval, aidx);
    acombineK<<<dim3(NPTS/256), dim3(256), 0, stream>>>(aval, aidx, counts);
    ccMK    <<<dim3(NPTS/128, NSPL), dim3(256), 0, stream>>>(chh, chl, counts, sigma, cval, cidx);
    ccombineK<<<dim3(NPTS/256), dim3(256), 0, stream>>>(cval, cidx, counts, keep);
    keepwriteK<<<dim3(NPTS/256), dim3(256), 0, stream>>>(keep, out);
}